// Round 1
// baseline (94.291 us; speedup 1.0000x reference)
//
#include <hip/hip_runtime.h>
#include <math.h>

#define BATCH     128
#define N_NODES   32768
#define N_CHILD   65536
#define NNZ_TOTAL 1048576

// ---------------------------------------------------------------------------
// Kernel 1: ex[c][b] = exp(child_ll[b][c])  (tiled transpose through LDS)
// grid = N_CHILD/64 blocks, 256 threads
// ---------------------------------------------------------------------------
__global__ __launch_bounds__(256) void exp_transpose_kernel(
    const float* __restrict__ child_ll, float* __restrict__ ex) {
    __shared__ float tile[64][BATCH + 1];  // +1 pad: conflict-free column writes
    const int c0 = blockIdx.x * 64;
    const int t  = threadIdx.x;

    // Load: lane-contiguous in c (coalesced 256B per wave), 4 batch rows/pass
    {
        const int cl = t & 63;
        const int b0 = t >> 6;  // 0..3
#pragma unroll
        for (int j = 0; j < BATCH / 4; ++j) {
            const int b = b0 + j * 4;
            tile[cl][b] = expf(child_ll[(size_t)b * N_CHILD + c0 + cl]);
        }
    }
    __syncthreads();

    // Store: lane-contiguous in b (1KB contiguous per wave-instruction)
    {
        const int cl = t >> 5;         // 0..7
        const int b0 = (t & 31) * 4;   // 0..124
#pragma unroll
        for (int p = 0; p < 8; ++p) {
            const int c = p * 8 + cl;
            float4 v = make_float4(tile[c][b0], tile[c][b0 + 1],
                                   tile[c][b0 + 2], tile[c][b0 + 3]);
            *(float4*)&ex[(size_t)(c0 + c) * BATCH + b0] = v;
        }
    }
}

// ---------------------------------------------------------------------------
// Kernel 2: row_start[r] = lower_bound(rows, r); rows is sorted.
// ---------------------------------------------------------------------------
__global__ __launch_bounds__(256) void row_starts_kernel(
    const int* __restrict__ rows, int* __restrict__ row_start) {
    const int r = blockIdx.x * blockDim.x + threadIdx.x;
    if (r > N_NODES) return;
    if (r == N_NODES) { row_start[r] = NNZ_TOTAL; return; }
    int lo = 0, hi = NNZ_TOTAL;
    while (lo < hi) {
        const int mid = (lo + hi) >> 1;
        if (rows[mid] < r) lo = mid + 1; else hi = mid;
    }
    row_start[r] = lo;
}

// ---------------------------------------------------------------------------
// Kernel 3: per-row segment sum. One block (128 threads) per row; thread =
// batch sample. Gather from transposed exp table is a coalesced 512B load.
// ---------------------------------------------------------------------------
#define CHUNK 128

__global__ __launch_bounds__(128) void sum_rows_kernel(
    const float* __restrict__ ex, const float* __restrict__ log_w,
    const int* __restrict__ cols, const int* __restrict__ row_start,
    float* __restrict__ out) {
    // XCD-aware swizzle: consecutive r on the same XCD (32768 % 8 == 0)
    const int bid = blockIdx.x;
    const int r   = (bid & 7) * (N_NODES / 8) + (bid >> 3);
    const int t   = threadIdx.x;  // batch index

    const int start = row_start[r];
    const int end   = row_start[r + 1];

    __shared__ float s_w[CHUNK];
    __shared__ int   s_c[CHUNK];

    float acc  = 0.f;
    float wsum = 0.f;

    for (int base = start; base < end; base += CHUNK) {
        const int n = min(end - base, CHUNK);
        __syncthreads();
        if (t < n) {
            s_w[t] = expf(log_w[base + t]);
            s_c[t] = cols[base + t];
        }
        __syncthreads();
        for (int k = 0; k < n; ++k) {
            const float w = s_w[k];
            acc  += w * ex[(size_t)s_c[k] * BATCH + t];
            wsum += w;
        }
    }

    out[(size_t)t * N_NODES + r] = logf(acc) - logf(wsum);
}

// ---------------------------------------------------------------------------
extern "C" void kernel_launch(void* const* d_in, const int* in_sizes, int n_in,
                              void* d_out, int out_size, void* d_ws, size_t ws_size,
                              hipStream_t stream) {
    const float* child_ll = (const float*)d_in[0];
    const float* log_w    = (const float*)d_in[1];
    const int*   rows     = (const int*)d_in[2];
    const int*   cols     = (const int*)d_in[3];
    float*       out      = (float*)d_out;

    // workspace layout
    float* ex        = (float*)d_ws;                                   // 33.5 MB
    int*   row_start = (int*)((char*)d_ws + (size_t)N_CHILD * BATCH * 4); // 128KB

    exp_transpose_kernel<<<N_CHILD / 64, 256, 0, stream>>>(child_ll, ex);
    row_starts_kernel<<<(N_NODES + 256) / 256 + 1, 256, 0, stream>>>(rows, row_start);
    sum_rows_kernel<<<N_NODES, 128, 0, stream>>>(ex, log_w, cols, row_start, out);
}

// Round 2
// 90.306 us; speedup vs baseline: 1.0441x; 1.0441x over previous
//
#include <hip/hip_runtime.h>
#include <hip/hip_fp16.h>
#include <math.h>

#define BATCH     128
#define N_NODES   32768
#define N_CHILD   65536
#define NNZ_TOTAL 1048576

// ---------------------------------------------------------------------------
// Kernel 1: ex[c][b] = (half)exp(child_ll[b][c])  (tiled transpose via LDS)
// ---------------------------------------------------------------------------
__global__ __launch_bounds__(256) void exp_transpose_kernel(
    const float* __restrict__ child_ll, __half* __restrict__ ex) {
    __shared__ float tile[64][BATCH + 1];
    const int c0 = blockIdx.x * 64;
    const int t  = threadIdx.x;

    {
        const int cl = t & 63;
        const int b0 = t >> 6;  // 0..3
#pragma unroll
        for (int j = 0; j < BATCH / 4; ++j) {
            const int b = b0 + j * 4;
            tile[cl][b] = expf(child_ll[(size_t)b * N_CHILD + c0 + cl]);
        }
    }
    __syncthreads();

    {
        const int cl = t >> 5;         // 0..7
        const int b0 = (t & 31) * 4;   // 0..124
#pragma unroll
        for (int p = 0; p < 8; ++p) {
            const int c = p * 8 + cl;
            union { __half2 h[2]; uint2 u; } pack;
            pack.h[0] = __half2{__float2half(tile[c][b0]),     __float2half(tile[c][b0 + 1])};
            pack.h[1] = __half2{__float2half(tile[c][b0 + 2]), __float2half(tile[c][b0 + 3])};
            *(uint2*)&ex[(size_t)(c0 + c) * BATCH + b0] = pack.u;
        }
    }
}

// ---------------------------------------------------------------------------
// Kernel 2: w[i] = exp(log_w[i])   (vectorized, so sum kernel has no expf)
// ---------------------------------------------------------------------------
__global__ __launch_bounds__(256) void exp_w_kernel(
    const float* __restrict__ log_w, float* __restrict__ w) {
    const int i = (blockIdx.x * 256 + threadIdx.x) * 4;
    float4 v = *(const float4*)&log_w[i];
    v.x = expf(v.x); v.y = expf(v.y); v.z = expf(v.z); v.w = expf(v.w);
    *(float4*)&w[i] = v;
}

// ---------------------------------------------------------------------------
// Kernel 3: row_start[r] = lower_bound(rows, r); rows is sorted.
// ---------------------------------------------------------------------------
__global__ __launch_bounds__(256) void row_starts_kernel(
    const int* __restrict__ rows, int* __restrict__ row_start) {
    const int r = blockIdx.x * blockDim.x + threadIdx.x;
    if (r > N_NODES) return;
    if (r == N_NODES) { row_start[r] = NNZ_TOTAL; return; }
    int lo = 0, hi = NNZ_TOTAL;
    while (lo < hi) {
        const int mid = (lo + hi) >> 1;
        if (rows[mid] < r) lo = mid + 1; else hi = mid;
    }
    row_start[r] = lo;
}

// ---------------------------------------------------------------------------
// Kernel 4: per-row sum. One WAVE per row (lane = 2 batch samples, half2
// gather = 256B/wave/nnz). 8-wide unrolled gather for MLP; cols/w are
// wave-uniform scalar loads.
// ---------------------------------------------------------------------------
__global__ __launch_bounds__(256) void sum_rows_kernel(
    const __half* __restrict__ ex, const float* __restrict__ w,
    const int* __restrict__ cols, const int* __restrict__ row_start,
    float* __restrict__ out) {
    const int wave = threadIdx.x >> 6;   // 0..3
    const int lane = threadIdx.x & 63;
    const int bid  = blockIdx.x;         // grid = N_NODES/4 = 8192, %8==0
    const int rb   = (bid & 7) * (N_NODES / 4 / 8) + (bid >> 3);  // XCD swizzle
    const int r    = rb * 4 + wave;

    const int start = row_start[r];
    const int end   = row_start[r + 1];
    const int b0    = lane * 2;

    float ax0 = 0.f, ay0 = 0.f, ax1 = 0.f, ay1 = 0.f;
    float ws0 = 0.f, ws1 = 0.f;

    for (int i = start; i < end; i += 8) {
        int   cc[8];
        float ww[8];
#pragma unroll
        for (int j = 0; j < 8; ++j) {
            const int idx = i + j;
            const bool v  = idx < end;       // wave-uniform branch
            cc[j] = v ? cols[idx] : 0;
            ww[j] = v ? w[idx] : 0.f;
        }
        __half2 g[8];
#pragma unroll
        for (int j = 0; j < 8; ++j)
            g[j] = *(const __half2*)&ex[((size_t)cc[j] << 7) + b0];
#pragma unroll
        for (int j = 0; j < 8; ++j) {
            const float2 f = __half22float2(g[j]);
            if (j & 1) { ax1 += ww[j] * f.x; ay1 += ww[j] * f.y; ws1 += ww[j]; }
            else       { ax0 += ww[j] * f.x; ay0 += ww[j] * f.y; ws0 += ww[j]; }
        }
    }

    const float accx = ax0 + ax1;
    const float accy = ay0 + ay1;
    const float logz = logf(ws0 + ws1);

    out[(size_t)b0 * N_NODES + r]       = logf(accx) - logz;
    out[(size_t)(b0 + 1) * N_NODES + r] = logf(accy) - logz;
}

// ---------------------------------------------------------------------------
extern "C" void kernel_launch(void* const* d_in, const int* in_sizes, int n_in,
                              void* d_out, int out_size, void* d_ws, size_t ws_size,
                              hipStream_t stream) {
    const float* child_ll = (const float*)d_in[0];
    const float* log_w    = (const float*)d_in[1];
    const int*   rows     = (const int*)d_in[2];
    const int*   cols     = (const int*)d_in[3];
    float*       out      = (float*)d_out;

    // workspace layout
    __half* ex        = (__half*)d_ws;                                        // 16.78 MB
    float*  w         = (float*)((char*)d_ws + (size_t)N_CHILD * BATCH * 2);  // 4 MB
    int*    row_start = (int*)((char*)w + (size_t)NNZ_TOTAL * 4);             // 128 KB

    exp_transpose_kernel<<<N_CHILD / 64, 256, 0, stream>>>(child_ll, ex);
    exp_w_kernel<<<NNZ_TOTAL / 1024, 256, 0, stream>>>(log_w, w);
    row_starts_kernel<<<(N_NODES + 256) / 256 + 1, 256, 0, stream>>>(rows, row_start);
    sum_rows_kernel<<<N_NODES / 4, 256, 0, stream>>>(ex, w, cols, row_start, out);
}

// Round 3
// 69.293 us; speedup vs baseline: 1.3608x; 1.3032x over previous
//
#include <hip/hip_runtime.h>
#include <hip/hip_fp16.h>
#include <math.h>

#define BATCH     128
#define N_NODES   32768
#define N_CHILD   65536
#define NNZ_TOTAL 1048576
#define NMAX      64

// ---------------------------------------------------------------------------
// Kernel 1: ex[c][b] = (half)exp(child_ll[b][c])  (tiled transpose via LDS)
// ---------------------------------------------------------------------------
__global__ __launch_bounds__(256) void exp_transpose_kernel(
    const float* __restrict__ child_ll, __half* __restrict__ ex) {
    __shared__ float tile[64][BATCH + 1];
    const int c0 = blockIdx.x * 64;
    const int t  = threadIdx.x;

    {
        const int cl = t & 63;
        const int b0 = t >> 6;  // 0..3
#pragma unroll
        for (int j = 0; j < BATCH / 4; ++j) {
            const int b = b0 + j * 4;
            tile[cl][b] = expf(child_ll[(size_t)b * N_CHILD + c0 + cl]);
        }
    }
    __syncthreads();

    {
        const int cl = t >> 5;         // 0..7
        const int b0 = (t & 31) * 4;   // 0..124
#pragma unroll
        for (int p = 0; p < 8; ++p) {
            const int c = p * 8 + cl;
            union { __half2 h[2]; uint2 u; } pack;
            pack.h[0] = __half2{__float2half(tile[c][b0]),     __float2half(tile[c][b0 + 1])};
            pack.h[1] = __half2{__float2half(tile[c][b0 + 2]), __float2half(tile[c][b0 + 3])};
            *(uint2*)&ex[(size_t)(c0 + c) * BATCH + b0] = pack.u;
        }
    }
}

// ---------------------------------------------------------------------------
// Kernel 2: w[i] = exp(log_w[i])
// ---------------------------------------------------------------------------
__global__ __launch_bounds__(256) void exp_w_kernel(
    const float* __restrict__ log_w, float* __restrict__ w) {
    const int i = (blockIdx.x * 256 + threadIdx.x) * 4;
    float4 v = *(const float4*)&log_w[i];
    v.x = expf(v.x); v.y = expf(v.y); v.z = expf(v.z); v.w = expf(v.w);
    *(float4*)&w[i] = v;
}

// ---------------------------------------------------------------------------
// Kernel 3: row_start[r] = lower_bound(rows, r); rows is sorted.
// ---------------------------------------------------------------------------
__global__ __launch_bounds__(256) void row_starts_kernel(
    const int* __restrict__ rows, int* __restrict__ row_start) {
    const int r = blockIdx.x * blockDim.x + threadIdx.x;
    if (r > N_NODES) return;
    if (r == N_NODES) { row_start[r] = NNZ_TOTAL; return; }
    int lo = 0, hi = NNZ_TOTAL;
    while (lo < hi) {
        const int mid = (lo + hi) >> 1;
        if (rows[mid] < r) lo = mid + 1; else hi = mid;
    }
    row_start[r] = lo;
}

// ---------------------------------------------------------------------------
// Kernel 4: per-row sum, one wave per row. Lane-cooperative cols/w load,
// v_readlane broadcast, ALL 64 gathers issued before first consume
// (2 memory round-trips per row instead of 8).
// ---------------------------------------------------------------------------
__global__ __launch_bounds__(256, 4) void sum_rows_kernel(
    const __half* __restrict__ ex, const float* __restrict__ w,
    const int* __restrict__ cols, const int* __restrict__ row_start,
    float* __restrict__ out) {
    const int wave = threadIdx.x >> 6;   // 0..3
    const int lane = threadIdx.x & 63;
    const int bid  = blockIdx.x;         // grid = 8192, %8==0
    const int rb   = (bid & 7) * (N_NODES / 4 / 8) + (bid >> 3);  // XCD swizzle
    const int r    = rb * 4 + wave;

    const int start = row_start[r];
    const int end   = row_start[r + 1];
    const int b0    = lane * 2;

    float accx = 0.f, accy = 0.f, wsum = 0.f;

    for (int base = start; base < end; base += NMAX) {
        const int idx  = base + lane;
        const bool v   = idx < end;
        // cooperative coalesced loads; OOB lanes clamp (weight forced to 0)
        const int   c  = __builtin_nontemporal_load(&cols[min(idx, NNZ_TOTAL - 1)]);
        const float wv = v ? __builtin_nontemporal_load(&w[idx]) : 0.f;
        const int  seg = min(end - base, NMAX);

        // Phase 1: issue ALL gathers (scalar base from readlane -> saddr form)
        __half2 g[NMAX];
#pragma unroll
        for (int j = 0; j < NMAX; ++j) {
            const int cj = __builtin_amdgcn_readlane(c, j);
            g[j] = *(const __half2*)&ex[((size_t)(unsigned)cj << 7) + b0];
        }

        // Phase 2: consume (16-group early-out, wave-uniform branch)
#pragma unroll
        for (int jb = 0; jb < NMAX; jb += 16) {
            if (jb >= seg) break;
#pragma unroll
            for (int jj = 0; jj < 16; ++jj) {
                const int j = jb + jj;
                const float wj = __uint_as_float(
                    __builtin_amdgcn_readlane(__float_as_uint(wv), j));
                const float2 f = __half22float2(g[j]);
                accx += wj * f.x;
                accy += wj * f.y;
                wsum += wj;
            }
        }
    }

    const float logz = logf(wsum);
    out[(size_t)b0 * N_NODES + r]       = logf(accx) - logz;
    out[(size_t)(b0 + 1) * N_NODES + r] = logf(accy) - logz;
}

// ---------------------------------------------------------------------------
extern "C" void kernel_launch(void* const* d_in, const int* in_sizes, int n_in,
                              void* d_out, int out_size, void* d_ws, size_t ws_size,
                              hipStream_t stream) {
    const float* child_ll = (const float*)d_in[0];
    const float* log_w    = (const float*)d_in[1];
    const int*   rows     = (const int*)d_in[2];
    const int*   cols     = (const int*)d_in[3];
    float*       out      = (float*)d_out;

    __half* ex        = (__half*)d_ws;                                        // 16.78 MB
    float*  w         = (float*)((char*)d_ws + (size_t)N_CHILD * BATCH * 2);  // 4 MB
    int*    row_start = (int*)((char*)w + (size_t)NNZ_TOTAL * 4);             // 128 KB

    exp_transpose_kernel<<<N_CHILD / 64, 256, 0, stream>>>(child_ll, ex);
    exp_w_kernel<<<NNZ_TOTAL / 1024, 256, 0, stream>>>(log_w, w);
    row_starts_kernel<<<(N_NODES + 256) / 256 + 1, 256, 0, stream>>>(rows, row_start);
    sum_rows_kernel<<<N_NODES / 4, 256, 0, stream>>>(ex, w, cols, row_start, out);
}

// Round 4
// 67.441 us; speedup vs baseline: 1.3981x; 1.0275x over previous
//
#include <hip/hip_runtime.h>
#include <hip/hip_fp16.h>
#include <math.h>

#define BATCH     128
#define N_NODES   32768
#define N_CHILD   65536
#define NNZ_TOTAL 1048576

// ---------------------------------------------------------------------------
// Kernel 1: ex[c][b] = (half)exp(child_ll[b][c])  (tiled transpose via LDS)
// ---------------------------------------------------------------------------
__global__ __launch_bounds__(256) void exp_transpose_kernel(
    const float* __restrict__ child_ll, __half* __restrict__ ex) {
    __shared__ float tile[64][BATCH + 1];
    const int c0 = blockIdx.x * 64;
    const int t  = threadIdx.x;

    {
        const int cl = t & 63;
        const int b0 = t >> 6;  // 0..3
#pragma unroll
        for (int j = 0; j < BATCH / 4; ++j) {
            const int b = b0 + j * 4;
            tile[cl][b] = expf(child_ll[(size_t)b * N_CHILD + c0 + cl]);
        }
    }
    __syncthreads();

    {
        const int cl = t >> 4;         // 0..15
        const int b0 = (t & 15) * 8;   // 0..120
#pragma unroll
        for (int p = 0; p < 4; ++p) {
            const int c = p * 16 + cl;
            union { __half2 h[4]; uint4 u; } pk;
#pragma unroll
            for (int k = 0; k < 4; ++k)
                pk.h[k] = __half2{__float2half(tile[c][b0 + 2 * k]),
                                  __float2half(tile[c][b0 + 2 * k + 1])};
            *(uint4*)&ex[(size_t)(c0 + c) * BATCH + b0] = pk.u;
        }
    }
}

// ---------------------------------------------------------------------------
// Kernel 2: w[i] = exp(log_w[i])
// ---------------------------------------------------------------------------
__global__ __launch_bounds__(256) void exp_w_kernel(
    const float* __restrict__ log_w, float* __restrict__ w) {
    const int i = (blockIdx.x * 256 + threadIdx.x) * 4;
    float4 v = *(const float4*)&log_w[i];
    v.x = expf(v.x); v.y = expf(v.y); v.z = expf(v.z); v.w = expf(v.w);
    *(float4*)&w[i] = v;
}

// ---------------------------------------------------------------------------
// Kernel 3: row_start[r] = lower_bound(rows, r); rows is sorted.
// ---------------------------------------------------------------------------
__global__ __launch_bounds__(256) void row_starts_kernel(
    const int* __restrict__ rows, int* __restrict__ row_start) {
    const int r = blockIdx.x * blockDim.x + threadIdx.x;
    if (r > N_NODES) return;
    if (r == N_NODES) { row_start[r] = NNZ_TOTAL; return; }
    int lo = 0, hi = NNZ_TOTAL;
    while (lo < hi) {
        const int mid = (lo + hi) >> 1;
        if (rows[mid] < r) lo = mid + 1; else hi = mid;
    }
    row_start[r] = lo;
}

// ---------------------------------------------------------------------------
// Kernel 4: per-row sum, one wave per row. Seg-bounded 16-granule gather
// pipeline (double-buffered, 16 loads in flight), saddr+voffset addressing,
// wave-parallel wsum.
// ---------------------------------------------------------------------------
__global__ __launch_bounds__(256, 4) void sum_rows_kernel(
    const __half* __restrict__ ex, const float* __restrict__ w,
    const int* __restrict__ cols, const int* __restrict__ row_start,
    float* __restrict__ out) {
    const int wave = threadIdx.x >> 6;   // 0..3
    const int lane = threadIdx.x & 63;
    const int bid  = blockIdx.x;         // grid = 8192, %8==0
    const int rb   = (bid & 7) * (N_NODES / 4 / 8) + (bid >> 3);  // XCD swizzle
    const int r    = rb * 4 + wave;

    const int start = row_start[r];
    const int end   = row_start[r + 1];
    const char* exb = (const char*)ex;
    const unsigned bo = (unsigned)lane * 4u;  // byte offset within a 256B row

    float accx = 0.f, accy = 0.f, wlane = 0.f;

    for (int base = start; base < end; base += 64) {
        const int  idx   = base + lane;
        const bool valid = idx < end;
        const int  cidx  = valid ? idx : start;   // clamp inside segment (warm line)
        const int  c     = __builtin_nontemporal_load(&cols[cidx]);
        const float wv   = valid ? __builtin_nontemporal_load(&w[idx]) : 0.f;
        wlane += wv;
        const int seg = end - base;               // wave-uniform

        __half2 ga[16], gb[16];

        // prologue: granule 0 (always issued; garbage lanes weighted 0)
#pragma unroll
        for (int jj = 0; jj < 16; ++jj) {
            const unsigned cj = (unsigned)__builtin_amdgcn_readlane(c, jj);
            ga[jj] = *(const __half2*)(exb + ((size_t)cj << 8) + bo);
        }

#pragma unroll
        for (int t16 = 0; t16 < 4; ++t16) {
            // prefetch next granule while current consumes (16 loads in flight)
            if (t16 < 3 && (t16 + 1) * 16 < seg) {
#pragma unroll
                for (int jj = 0; jj < 16; ++jj) {
                    const int j = (t16 + 1) * 16 + jj;
                    const unsigned cj = (unsigned)__builtin_amdgcn_readlane(c, j);
                    gb[jj] = *(const __half2*)(exb + ((size_t)cj << 8) + bo);
                }
            }
            // consume current granule (wave-uniform skip for short rows)
            if (t16 * 16 < seg) {
#pragma unroll
                for (int jj = 0; jj < 16; ++jj) {
                    const int j = t16 * 16 + jj;
                    const float wj = __uint_as_float(
                        __builtin_amdgcn_readlane(__float_as_uint(wv), j));
                    const __half2 g = ga[jj];
                    accx = fmaf(wj, __half2float(__low2half(g)), accx);
                    accy = fmaf(wj, __half2float(__high2half(g)), accy);
                }
            }
            // rotate buffers (register-renamed away after full unroll)
#pragma unroll
            for (int jj = 0; jj < 16; ++jj) ga[jj] = gb[jj];
        }
    }

    // wave-parallel normalization sum
    float wsum = wlane;
#pragma unroll
    for (int m = 1; m < 64; m <<= 1) wsum += __shfl_xor(wsum, m, 64);
    const float logz = logf(wsum);

    const int b = lane * 2;
    out[(size_t)b * N_NODES + r]       = logf(accx) - logz;
    out[(size_t)(b + 1) * N_NODES + r] = logf(accy) - logz;
}

// ---------------------------------------------------------------------------
extern "C" void kernel_launch(void* const* d_in, const int* in_sizes, int n_in,
                              void* d_out, int out_size, void* d_ws, size_t ws_size,
                              hipStream_t stream) {
    const float* child_ll = (const float*)d_in[0];
    const float* log_w    = (const float*)d_in[1];
    const int*   rows     = (const int*)d_in[2];
    const int*   cols     = (const int*)d_in[3];
    float*       out      = (float*)d_out;

    __half* ex        = (__half*)d_ws;                                        // 16.78 MB
    float*  w         = (float*)((char*)d_ws + (size_t)N_CHILD * BATCH * 2);  // 4 MB
    int*    row_start = (int*)((char*)w + (size_t)NNZ_TOTAL * 4);             // 128 KB

    exp_transpose_kernel<<<N_CHILD / 64, 256, 0, stream>>>(child_ll, ex);
    exp_w_kernel<<<NNZ_TOTAL / 1024, 256, 0, stream>>>(log_w, w);
    row_starts_kernel<<<(N_NODES + 256) / 256 + 1, 256, 0, stream>>>(rows, row_start);
    sum_rows_kernel<<<N_NODES / 4, 256, 0, stream>>>(ex, w, cols, row_start, out);
}